// Round 4
// baseline (169.834 us; speedup 1.0000x reference)
//
#include <hip/hip_runtime.h>
#include <hip/hip_bf16.h>

#define NB   16
#define LQ   300
#define LV   8400
#define CDIM 256
#define NH   8
#define HD   32
#define NL   3
#define NP   4

typedef __bf16 bf16x8 __attribute__((ext_vector_type(8)));
typedef float  f32x4  __attribute__((ext_vector_type(4)));

typedef __attribute__((address_space(1))) const void gv_t;
typedef __attribute__((address_space(3))) void lv_t;
#define GLOAD16(g, l) __builtin_amdgcn_global_load_lds((gv_t*)(g), (lv_t*)(l), 16, 0, 0)

// ---------------------------------------------------------------------------
// qproj: 8 queries per block. off = q@W_off+b_off ; aw = softmax per-head-12.
// ---------------------------------------------------------------------------
__global__ __launch_bounds__(256) void qproj_kernel(
    const float* __restrict__ query, const float* __restrict__ W_off,
    const float* __restrict__ b_off, const float* __restrict__ W_attn,
    const float* __restrict__ b_attn, float* __restrict__ off_out,
    float* __restrict__ aw_out)
{
    int b = blockIdx.x;             // 0..599
    int t = threadIdx.x;            // 0..255
    __shared__ float qs[8][CDIM];
    __shared__ float lg[8][96];

    #pragma unroll
    for (int g = 0; g < 8; ++g)
        qs[g][t] = query[((size_t)b * 8 + g) * CDIM + t];
    __syncthreads();

    #pragma unroll
    for (int pass = 0; pass < 2; ++pass) {
        int c = pass * 256 + t;
        if (c < 288) {
            bool isoff = c < 192;
            float acc[8] = {};
            #pragma unroll 4
            for (int k = 0; k < CDIM; ++k) {
                float w = isoff ? W_off[k * 192 + c] : W_attn[k * 96 + (c - 192)];
                #pragma unroll
                for (int g = 0; g < 8; ++g) acc[g] += qs[g][k] * w;
            }
            if (isoff) {
                float bv = b_off[c];
                #pragma unroll
                for (int g = 0; g < 8; ++g)
                    off_out[((size_t)b * 8 + g) * 192 + c] = acc[g] + bv;
            } else {
                float bv = b_attn[c - 192];
                #pragma unroll
                for (int g = 0; g < 8; ++g)
                    lg[g][c - 192] = acc[g] + bv;
            }
        }
    }
    __syncthreads();
    if (t < 64) {
        int g = t >> 3, h = t & 7;
        float m = -1e30f;
        #pragma unroll
        for (int i = 0; i < 12; ++i) m = fmaxf(m, lg[g][h * 12 + i]);
        float s = 0.f;
        #pragma unroll
        for (int i = 0; i < 12; ++i) s += expf(lg[g][h * 12 + i] - m);
        float inv = 1.f / s;
        #pragma unroll
        for (int i = 0; i < 12; ++i)
            aw_out[((size_t)b * 8 + g) * 96 + h * 12 + i] =
                expf(lg[g][h * 12 + i] - m) * inv;
    }
}

// ---------------------------------------------------------------------------
// W transpose + bf16 convert: Wt[n][k] = bf16(W[k][n]); 256x256 each.
// ---------------------------------------------------------------------------
__global__ __launch_bounds__(256) void wtrans_kernel(
    const float* __restrict__ Wv, const float* __restrict__ Wo,
    __bf16* __restrict__ Wtv, __bf16* __restrict__ Wto)
{
    const float* W = blockIdx.z ? Wo : Wv;
    __bf16* Wt = blockIdx.z ? Wto : Wtv;
    __shared__ float tile[32][33];
    int tx = threadIdx.x & 31, ty = threadIdx.x >> 5;   // 32x8
    int n0 = blockIdx.x * 32, k0 = blockIdx.y * 32;
    #pragma unroll
    for (int i = 0; i < 32; i += 8)
        tile[ty + i][tx] = W[(size_t)(k0 + ty + i) * 256 + n0 + tx];
    __syncthreads();
    #pragma unroll
    for (int i = 0; i < 32; i += 8)
        Wt[(size_t)(n0 + ty + i) * 256 + k0 + tx] = (__bf16)tile[tx][ty + i];
}

// ---------------------------------------------------------------------------
// 2-phase double-buffered MFMA GEMM: C[M,256] = A_f32[M,256] @ Bt^T + bias.
// BM=BN=128, BK=64, 4 waves. global_load_lds staging, XOR-swizzled global
// source (linear LDS dest, rule #21), swizzled ds_read_b128 reads (0 bank
// conflicts, verified round 3). Double-buffer: STAGE(t+1) issued BEFORE
// compute(t); single vmcnt(0)+barrier per tile (catalog T3-minimum) keeps
// 48 KB of loads in flight during compute+drain -> HBM stays saturated.
// LDS 96 KB -> 1 block/CU.
// ---------------------------------------------------------------------------
template<bool C_F32, bool GUARD>
__global__ __launch_bounds__(256) void gemm_2ph(
    const float* __restrict__ A, const __bf16* __restrict__ Bt,
    const float* __restrict__ bias, void* __restrict__ Cptr, int M)
{
    __shared__ float  As[2][128][64];   // 64 KB
    __shared__ __bf16 Bs[2][128][64];   // 32 KB
    int tid  = threadIdx.x;
    int lane = tid & 63, wid = tid >> 6;
    int wr = wid >> 1, wc = wid & 1;
    int r16 = lane & 15, kgrp = lane >> 4;
    int bm = blockIdx.y, bn = blockIdx.x;

    f32x4 acc[4][4];
    #pragma unroll
    for (int m = 0; m < 4; ++m)
        #pragma unroll
        for (int n = 0; n < 4; ++n)
            acc[m][n] = (f32x4){0.f, 0.f, 0.f, 0.f};

    // ---- staging macro (buf, kt compile-time after unroll) ----
    auto STAGE = [&](int buf, int kt) {
        #pragma unroll
        for (int i = 0; i < 8; ++i) {           // A: 8 loads x 4 rows
            int rowbase = (wid * 8 + i) * 4;
            int r  = rowbase + (lane >> 4);
            int grow = bm * 128 + r;
            if (GUARD) grow = grow < M ? grow : M - 1;
            int gs = (lane & 15) ^ (r & 15);
            GLOAD16(A + ((size_t)grow * 256 + kt) + gs * 4, &As[buf][rowbase][0]);
        }
        #pragma unroll
        for (int i = 0; i < 4; ++i) {           // B: 4 loads x 8 rows
            int rowbase = (wid * 4 + i) * 8;
            int r  = rowbase + (lane >> 3);
            int gs = (lane & 7) ^ (r & 7);
            GLOAD16(Bt + ((size_t)(bn * 128 + r) * 256 + kt) + gs * 8,
                    &Bs[buf][rowbase][0]);
        }
    };

    STAGE(0, 0);
    __syncthreads();                 // vmcnt(0) drain + barrier

    #pragma unroll
    for (int t = 0; t < 4; ++t) {
        int buf = t & 1;
        if (t < 3) STAGE(buf ^ 1, (t + 1) * 64);   // prefetch next tile
        // ---- compute on buf ----
        #pragma unroll
        for (int kk = 0; kk < 64; kk += 32) {
            bf16x8 af[4], bfg[4];
            #pragma unroll
            for (int m = 0; m < 4; ++m) {
                int R = wr * 64 + m * 16 + r16;
                int g = (kk + kgrp * 8) >> 2;
                f32x4 lo = *(const f32x4*)&As[buf][R][(g ^ (R & 15)) << 2];
                f32x4 hi = *(const f32x4*)&As[buf][R][((g + 1) ^ (R & 15)) << 2];
                bf16x8 tv;
                tv[0] = (__bf16)lo[0]; tv[1] = (__bf16)lo[1];
                tv[2] = (__bf16)lo[2]; tv[3] = (__bf16)lo[3];
                tv[4] = (__bf16)hi[0]; tv[5] = (__bf16)hi[1];
                tv[6] = (__bf16)hi[2]; tv[7] = (__bf16)hi[3];
                af[m] = tv;
            }
            #pragma unroll
            for (int n = 0; n < 4; ++n) {
                int R = wc * 64 + n * 16 + r16;
                int g = (kk + kgrp * 8) >> 3;
                bfg[n] = *(const bf16x8*)&Bs[buf][R][(g ^ (R & 7)) << 3];
            }
            #pragma unroll
            for (int m = 0; m < 4; ++m)
                #pragma unroll
                for (int n = 0; n < 4; ++n)
                    acc[m][n] = __builtin_amdgcn_mfma_f32_16x16x32_bf16(
                        af[m], bfg[n], acc[m][n], 0, 0, 0);
        }
        __syncthreads();             // drains next-tile loads (vmcnt 0) + bar
    }

    int crow0 = bm * 128 + wr * 64;
    int ccol0 = bn * 128 + wc * 64;
    #pragma unroll
    for (int n = 0; n < 4; ++n) {
        int col = ccol0 + n * 16 + r16;
        float bv = bias[col];
        #pragma unroll
        for (int m = 0; m < 4; ++m)
            #pragma unroll
            for (int r = 0; r < 4; ++r) {
                int row = crow0 + m * 16 + kgrp * 4 + r;
                if (!GUARD || row < M) {
                    float val = acc[m][n][r] + bv;
                    if (C_F32) ((float*)Cptr)[(size_t)row * 256 + col] = val;
                    else       ((__bf16*)Cptr)[(size_t)row * 256 + col] = (__bf16)val;
                }
            }
    }
}

// ---------------------------------------------------------------------------
// Sampler: 2 queries/block. Phase 1 (192 thr): coords/weights -> LDS with
// weight pre-multiplied by attention and zeroed when OOB. Phase 2: 2 ch/lane
// ushort2 gathers.
// ---------------------------------------------------------------------------
__global__ __launch_bounds__(256) void sample_kernel(
    const __bf16* __restrict__ v, const float* __restrict__ offb,
    const float* __restrict__ awb, const float* __restrict__ refp,
    float* __restrict__ mid)
{
    int b = blockIdx.x;              // 0..2399
    int t = threadIdx.x;
    __shared__ int   offs[2][96][4];
    __shared__ float wgt [2][96][4];

    const int Hs[NL]  = {80, 40, 20};
    const int Wd[NL]  = {80, 40, 20};
    const int lvo[NL] = {0, 6400, 8000};

    if (t < 192) {
        int q2  = t >= 96;
        int idx = t - q2 * 96;       // h*12 + l*4 + p
        int nq  = b * 2 + q2;
        int lp = idx % 12, l = lp >> 2, p = lp & 3;
        int h = idx / 12;
        const float* rpq = refp + (size_t)nq * 12 + l * 4;
        float cx = rpq[0], cy = rpq[1], rw = rpq[2], rh = rpq[3];
        float ox = offb[(size_t)nq * 192 + ((h * NL + l) * NP + p) * 2 + 0];
        float oy = offb[(size_t)nq * 192 + ((h * NL + l) * NP + p) * 2 + 1];
        float a  = awb [(size_t)nq * 96 + idx];
        int W = Wd[l], H = Hs[l];
        float x = (cx + ox * 0.125f * rw) * (float)W - 0.5f;
        float y = (cy + oy * 0.125f * rh) * (float)H - 0.5f;
        float x0f = floorf(x), y0f = floorf(y);
        int x0 = (int)x0f, y0 = (int)y0f;
        float wx1 = x - x0f, wy1 = y - y0f;
        float wx0 = 1.f - wx1, wy0 = 1.f - wy1;
        float w4[4] = {wx0 * wy0, wx1 * wy0, wx0 * wy1, wx1 * wy1};
        int   xs[4] = {x0, x0 + 1, x0, x0 + 1};
        int   ys[4] = {y0, y0, y0 + 1, y0 + 1};
        #pragma unroll
        for (int cc = 0; cc < 4; ++cc) {
            bool valid = (xs[cc] >= 0) & (xs[cc] < W) & (ys[cc] >= 0) & (ys[cc] < H);
            offs[q2][idx][cc] = valid ? (lvo[l] + ys[cc] * W + xs[cc]) * 256 : 0;
            wgt [q2][idx][cc] = valid ? a * w4[cc] : 0.f;
        }
    }
    __syncthreads();

    int q2 = t >> 7, r = t & 127;
    int h = r >> 4, c2 = r & 15;
    int nq = b * 2 + q2, n = nq / LQ;
    const __bf16* vb = v + (size_t)n * LV * 256 + h * 32 + c2 * 2;
    float a0 = 0.f, a1 = 0.f;
    #pragma unroll
    for (int lp = 0; lp < 12; ++lp) {
        int idx = h * 12 + lp;
        #pragma unroll
        for (int cc = 0; cc < 4; ++cc) {
            float w = wgt[q2][idx][cc];
            int   e = offs[q2][idx][cc];
            ushort2 u = *(const ushort2*)&vb[e];
            a0 += w * __uint_as_float(((unsigned)u.x) << 16);
            a1 += w * __uint_as_float(((unsigned)u.y) << 16);
        }
    }
    float2 o = {a0, a1};
    *(float2*)&mid[(size_t)nq * 256 + h * 32 + c2 * 2] = o;
}

// ---------------------------------------------------------------------------
extern "C" void kernel_launch(void* const* d_in, const int* in_sizes, int n_in,
                              void* d_out, int out_size, void* d_ws, size_t ws_size,
                              hipStream_t stream)
{
    const float* query  = (const float*)d_in[0];
    const float* refp   = (const float*)d_in[1];
    const float* value  = (const float*)d_in[2];
    const float* W_off  = (const float*)d_in[3];
    const float* b_off  = (const float*)d_in[4];
    const float* W_attn = (const float*)d_in[5];
    const float* b_attn = (const float*)d_in[6];
    const float* W_val  = (const float*)d_in[7];
    const float* b_val  = (const float*)d_in[8];
    const float* W_out  = (const float*)d_in[9];
    const float* b_out  = (const float*)d_in[10];
    float* out = (float*)d_out;

    char* ws = (char*)d_ws;
    __bf16* v    = (__bf16*)ws;                                  // 68,812,800 B
    float*  offb = (float*)(ws + 68812800);                      //  3,686,400 B
    float*  awb  = (float*)(ws + 68812800 + 3686400);            //  1,843,200 B
    float*  mid  = (float*)(ws + 68812800 + 3686400 + 1843200);  //  4,915,200 B
    __bf16* Wtv  = (__bf16*)(ws + 68812800 + 3686400 + 1843200 + 4915200);
    __bf16* Wto  = Wtv + 65536;

    wtrans_kernel<<<dim3(8, 8, 2), 256, 0, stream>>>(W_val, W_out, Wtv, Wto);
    qproj_kernel<<<NB * LQ / 8, 256, 0, stream>>>(query, W_off, b_off, W_attn,
                                                  b_attn, offb, awb);
    // value projection: (134400 x 256) @ (256 x 256) + b_val -> bf16 v
    gemm_2ph<false, false><<<dim3(2, (NB * LV) / 128), 256, 0, stream>>>(
        value, Wtv, b_val, v, NB * LV);
    sample_kernel<<<NB * LQ / 2, 256, 0, stream>>>(v, offb, awb, refp, mid);
    // output projection: (4800 x 256) @ (256 x 256) + b_out -> fp32 out
    gemm_2ph<true, true><<<dim3(2, (NB * LQ + 127) / 128), 256, 0, stream>>>(
        mid, Wto, b_out, out, NB * LQ);
}

// Round 5
// 137.337 us; speedup vs baseline: 1.2366x; 1.2366x over previous
//
#include <hip/hip_runtime.h>
#include <hip/hip_bf16.h>

#define NB   16
#define LQ   300
#define LV   8400
#define CDIM 256
#define NH   8
#define HD   32
#define NL   3
#define NP   4

typedef __bf16 bf16x8 __attribute__((ext_vector_type(8)));
typedef float  f32x4  __attribute__((ext_vector_type(4)));

typedef __attribute__((address_space(1))) const void gv_t;
typedef __attribute__((address_space(3))) void lv_t;
#define GLOAD16(g, l) __builtin_amdgcn_global_load_lds((gv_t*)(g), (lv_t*)(l), 16, 0, 0)

// ---------------------------------------------------------------------------
// qproj: 8 queries per block. off = q@W_off+b_off ; aw = softmax per-head-12.
// ---------------------------------------------------------------------------
__global__ __launch_bounds__(256) void qproj_kernel(
    const float* __restrict__ query, const float* __restrict__ W_off,
    const float* __restrict__ b_off, const float* __restrict__ W_attn,
    const float* __restrict__ b_attn, float* __restrict__ off_out,
    float* __restrict__ aw_out)
{
    int b = blockIdx.x;             // 0..599
    int t = threadIdx.x;            // 0..255
    __shared__ float qs[8][CDIM];
    __shared__ float lg[8][96];

    #pragma unroll
    for (int g = 0; g < 8; ++g)
        qs[g][t] = query[((size_t)b * 8 + g) * CDIM + t];
    __syncthreads();

    #pragma unroll
    for (int pass = 0; pass < 2; ++pass) {
        int c = pass * 256 + t;
        if (c < 288) {
            bool isoff = c < 192;
            float acc[8] = {};
            #pragma unroll 4
            for (int k = 0; k < CDIM; ++k) {
                float w = isoff ? W_off[k * 192 + c] : W_attn[k * 96 + (c - 192)];
                #pragma unroll
                for (int g = 0; g < 8; ++g) acc[g] += qs[g][k] * w;
            }
            if (isoff) {
                float bv = b_off[c];
                #pragma unroll
                for (int g = 0; g < 8; ++g)
                    off_out[((size_t)b * 8 + g) * 192 + c] = acc[g] + bv;
            } else {
                float bv = b_attn[c - 192];
                #pragma unroll
                for (int g = 0; g < 8; ++g)
                    lg[g][c - 192] = acc[g] + bv;
            }
        }
    }
    __syncthreads();
    if (t < 64) {
        int g = t >> 3, h = t & 7;
        float m = -1e30f;
        #pragma unroll
        for (int i = 0; i < 12; ++i) m = fmaxf(m, lg[g][h * 12 + i]);
        float s = 0.f;
        #pragma unroll
        for (int i = 0; i < 12; ++i) s += expf(lg[g][h * 12 + i] - m);
        float inv = 1.f / s;
        #pragma unroll
        for (int i = 0; i < 12; ++i)
            aw_out[((size_t)b * 8 + g) * 96 + h * 12 + i] =
                expf(lg[g][h * 12 + i] - m) * inv;
    }
}

// ---------------------------------------------------------------------------
// W transpose + bf16 convert: Wt[n][k] = bf16(W[k][n]); 256x256 each.
// ---------------------------------------------------------------------------
__global__ __launch_bounds__(256) void wtrans_kernel(
    const float* __restrict__ Wv, const float* __restrict__ Wo,
    __bf16* __restrict__ Wtv, __bf16* __restrict__ Wto)
{
    const float* W = blockIdx.z ? Wo : Wv;
    __bf16* Wt = blockIdx.z ? Wto : Wtv;
    __shared__ float tile[32][33];
    int tx = threadIdx.x & 31, ty = threadIdx.x >> 5;   // 32x8
    int n0 = blockIdx.x * 32, k0 = blockIdx.y * 32;
    #pragma unroll
    for (int i = 0; i < 32; i += 8)
        tile[ty + i][tx] = W[(size_t)(k0 + ty + i) * 256 + n0 + tx];
    __syncthreads();
    #pragma unroll
    for (int i = 0; i < 32; i += 8)
        Wt[(size_t)(n0 + ty + i) * 256 + k0 + tx] = (__bf16)tile[tx][ty + i];
}

// ---------------------------------------------------------------------------
// Value-projection GEMM: C_bf16[134400,256] = A_f32 @ Bt^T + bias.
// BM=128, BN=256 (grid.x=1: A read ONCE -> staged VMEM 403->269 MB),
// BK=32 (8 K-steps), double-buffered 64 KB LDS. VGPR (~215, acc 4x8) caps
// occupancy at 2 blocks/CU; 2x64 KB LDS also fits 2 blocks/CU -> dbuf is
// free this time (round-4 regression was 96 KB -> 1 block/CU).
// Staging via global_load_lds, XOR-swizzled global source + swizzled
// ds_read_b128 (A: granule^ (r&7); B: granule ^ (r&3) ^ ((r>>2)&3) --
// bank-enumerated to 2-way max, which is free per m136).
// ---------------------------------------------------------------------------
__global__ __launch_bounds__(256, 2) void gemm_vproj(
    const float* __restrict__ A, const __bf16* __restrict__ Bt,
    const float* __restrict__ bias, __bf16* __restrict__ C)
{
    __shared__ float  As[2][128][32];   // 32 KB
    __shared__ __bf16 Bs[2][256][32];   // 32 KB
    int tid  = threadIdx.x;
    int lane = tid & 63, wid = tid >> 6;
    int wr = wid >> 1, wc = wid & 1;
    int r16 = lane & 15, kgrp = lane >> 4;
    int bm = blockIdx.x;

    f32x4 acc[4][8];
    #pragma unroll
    for (int m = 0; m < 4; ++m)
        #pragma unroll
        for (int n = 0; n < 8; ++n)
            acc[m][n] = (f32x4){0.f, 0.f, 0.f, 0.f};

    auto STAGE = [&](int buf, int kt) {
        #pragma unroll
        for (int i = 0; i < 4; ++i) {      // A: 4 loads x 8 rows (128B/row)
            int rowbase = wid * 32 + i * 8;
            int r  = rowbase + (lane >> 3);
            int gs = (lane & 7) ^ (r & 7);
            GLOAD16(A + ((size_t)(bm * 128 + r) * 256 + kt) + gs * 4,
                    &As[buf][rowbase][0]);
        }
        #pragma unroll
        for (int i = 0; i < 4; ++i) {      // B: 4 loads x 16 rows (64B/row)
            int rowbase = wid * 64 + i * 16;
            int r  = rowbase + (lane >> 2);
            int gs = (lane & 3) ^ (r & 3) ^ ((r >> 2) & 3);
            GLOAD16(Bt + ((size_t)r * 256 + kt) + gs * 8,
                    &Bs[buf][rowbase][0]);
        }
    };

    STAGE(0, 0);
    __syncthreads();

    #pragma unroll
    for (int t = 0; t < 8; ++t) {
        int buf = t & 1;
        if (t < 7) STAGE(buf ^ 1, (t + 1) * 32);   // prefetch next K-step
        bf16x8 af[4], bfg[8];
        #pragma unroll
        for (int m = 0; m < 4; ++m) {
            int R  = wr * 64 + m * 16 + r16;
            int g0 = (2 * kgrp)     ^ (R & 7);
            int g1 = (2 * kgrp + 1) ^ (R & 7);
            f32x4 lo = *(const f32x4*)&As[buf][R][g0 * 4];
            f32x4 hi = *(const f32x4*)&As[buf][R][g1 * 4];
            bf16x8 tv;
            tv[0] = (__bf16)lo[0]; tv[1] = (__bf16)lo[1];
            tv[2] = (__bf16)lo[2]; tv[3] = (__bf16)lo[3];
            tv[4] = (__bf16)hi[0]; tv[5] = (__bf16)hi[1];
            tv[6] = (__bf16)hi[2]; tv[7] = (__bf16)hi[3];
            af[m] = tv;
        }
        #pragma unroll
        for (int n = 0; n < 8; ++n) {
            int R = wc * 128 + n * 16 + r16;
            int g = kgrp ^ (R & 3) ^ ((R >> 2) & 3);
            bfg[n] = *(const bf16x8*)&Bs[buf][R][g * 8];
        }
        #pragma unroll
        for (int m = 0; m < 4; ++m)
            #pragma unroll
            for (int n = 0; n < 8; ++n)
                acc[m][n] = __builtin_amdgcn_mfma_f32_16x16x32_bf16(
                    af[m], bfg[n], acc[m][n], 0, 0, 0);
        __syncthreads();
    }

    int crow0 = bm * 128 + wr * 64;
    int ccol0 = wc * 128;
    #pragma unroll
    for (int n = 0; n < 8; ++n) {
        int col = ccol0 + n * 16 + r16;
        float bv = bias[col];
        #pragma unroll
        for (int m = 0; m < 4; ++m)
            #pragma unroll
            for (int r = 0; r < 4; ++r) {
                int row = crow0 + m * 16 + kgrp * 4 + r;
                C[(size_t)row * 256 + col] = (__bf16)(acc[m][n][r] + bv);
            }
    }
}

// ---------------------------------------------------------------------------
// Reg-staged MFMA GEMM (round-3 proven) — used for the small out-projection.
// ---------------------------------------------------------------------------
#define LDST 72
template<bool A_F32, bool C_F32>
__global__ __launch_bounds__(256) void gemm_mfma(
    const void* __restrict__ Aptr, const __bf16* __restrict__ Bt,
    const float* __restrict__ bias, void* __restrict__ Cptr, int M)
{
    __shared__ __bf16 As[128][LDST];
    __shared__ __bf16 Bs[128][LDST];
    int tid = threadIdx.x;
    int lane = tid & 63, wid = tid >> 6;
    int wr = wid >> 1, wc = wid & 1;
    int r16 = lane & 15, kgrp = lane >> 4;
    int bm = blockIdx.y, bn = blockIdx.x;

    f32x4 acc[4][4];
    #pragma unroll
    for (int m = 0; m < 4; ++m)
        #pragma unroll
        for (int n = 0; n < 4; ++n)
            acc[m][n] = (f32x4){0.f, 0.f, 0.f, 0.f};

    for (int kt = 0; kt < 256; kt += 64) {
        if (A_F32) {
            const float* A = (const float*)Aptr;
            #pragma unroll
            for (int p = 0; p < 8; ++p) {
                int row = p * 16 + (tid >> 4);
                int grow = bm * 128 + row; if (grow >= M) grow = M - 1;
                int col = (tid & 15) * 4;
                float4 a = *(const float4*)&A[(size_t)grow * 256 + kt + col];
                __bf16 pk[4] = {(__bf16)a.x, (__bf16)a.y, (__bf16)a.z, (__bf16)a.w};
                *(int2*)&As[row][col] = *(const int2*)pk;
            }
        } else {
            const __bf16* A = (const __bf16*)Aptr;
            #pragma unroll
            for (int p = 0; p < 4; ++p) {
                int row = p * 32 + (tid >> 3);
                int grow = bm * 128 + row; if (grow >= M) grow = M - 1;
                int col = (tid & 7) * 8;
                *(int4*)&As[row][col] = *(const int4*)&A[(size_t)grow * 256 + kt + col];
            }
        }
        #pragma unroll
        for (int p = 0; p < 4; ++p) {
            int row = p * 32 + (tid >> 3);
            int col = (tid & 7) * 8;
            *(int4*)&Bs[row][col] = *(const int4*)&Bt[(size_t)(bn * 128 + row) * 256 + kt + col];
        }
        __syncthreads();
        #pragma unroll
        for (int kk = 0; kk < 64; kk += 32) {
            bf16x8 af[4], bfr[4];
            #pragma unroll
            for (int m = 0; m < 4; ++m)
                af[m] = *(const bf16x8*)&As[wr * 64 + m * 16 + r16][kk + kgrp * 8];
            #pragma unroll
            for (int n = 0; n < 4; ++n)
                bfr[n] = *(const bf16x8*)&Bs[wc * 64 + n * 16 + r16][kk + kgrp * 8];
            #pragma unroll
            for (int m = 0; m < 4; ++m)
                #pragma unroll
                for (int n = 0; n < 4; ++n)
                    acc[m][n] = __builtin_amdgcn_mfma_f32_16x16x32_bf16(
                        af[m], bfr[n], acc[m][n], 0, 0, 0);
        }
        __syncthreads();
    }

    int crow0 = bm * 128 + wr * 64;
    int ccol0 = bn * 128 + wc * 64;
    #pragma unroll
    for (int n = 0; n < 4; ++n) {
        int col = ccol0 + n * 16 + r16;
        float bv = bias[col];
        #pragma unroll
        for (int m = 0; m < 4; ++m)
            #pragma unroll
            for (int r = 0; r < 4; ++r) {
                int row = crow0 + m * 16 + kgrp * 4 + r;
                if (row < M) {
                    float val = acc[m][n][r] + bv;
                    if (C_F32) ((float*)Cptr)[(size_t)row * 256 + col] = val;
                    else       ((__bf16*)Cptr)[(size_t)row * 256 + col] = (__bf16)val;
                }
            }
    }
}

// ---------------------------------------------------------------------------
// Sampler: 2 queries/block. Phase 1 (192 thr): coords/weights -> LDS with
// weight pre-multiplied by attention and zeroed when OOB. Phase 2: 2 ch/lane
// ushort2 gathers.
// ---------------------------------------------------------------------------
__global__ __launch_bounds__(256) void sample_kernel(
    const __bf16* __restrict__ v, const float* __restrict__ offb,
    const float* __restrict__ awb, const float* __restrict__ refp,
    float* __restrict__ mid)
{
    int b = blockIdx.x;              // 0..2399
    int t = threadIdx.x;
    __shared__ int   offs[2][96][4];
    __shared__ float wgt [2][96][4];

    const int Hs[NL]  = {80, 40, 20};
    const int Wd[NL]  = {80, 40, 20};
    const int lvo[NL] = {0, 6400, 8000};

    if (t < 192) {
        int q2  = t >= 96;
        int idx = t - q2 * 96;       // h*12 + l*4 + p
        int nq  = b * 2 + q2;
        int lp = idx % 12, l = lp >> 2, p = lp & 3;
        int h = idx / 12;
        const float* rpq = refp + (size_t)nq * 12 + l * 4;
        float cx = rpq[0], cy = rpq[1], rw = rpq[2], rh = rpq[3];
        float ox = offb[(size_t)nq * 192 + ((h * NL + l) * NP + p) * 2 + 0];
        float oy = offb[(size_t)nq * 192 + ((h * NL + l) * NP + p) * 2 + 1];
        float a  = awb [(size_t)nq * 96 + idx];
        int W = Wd[l], H = Hs[l];
        float x = (cx + ox * 0.125f * rw) * (float)W - 0.5f;
        float y = (cy + oy * 0.125f * rh) * (float)H - 0.5f;
        float x0f = floorf(x), y0f = floorf(y);
        int x0 = (int)x0f, y0 = (int)y0f;
        float wx1 = x - x0f, wy1 = y - y0f;
        float wx0 = 1.f - wx1, wy0 = 1.f - wy1;
        float w4[4] = {wx0 * wy0, wx1 * wy0, wx0 * wy1, wx1 * wy1};
        int   xs[4] = {x0, x0 + 1, x0, x0 + 1};
        int   ys[4] = {y0, y0, y0 + 1, y0 + 1};
        #pragma unroll
        for (int cc = 0; cc < 4; ++cc) {
            bool valid = (xs[cc] >= 0) & (xs[cc] < W) & (ys[cc] >= 0) & (ys[cc] < H);
            offs[q2][idx][cc] = valid ? (lvo[l] + ys[cc] * W + xs[cc]) * 256 : 0;
            wgt [q2][idx][cc] = valid ? a * w4[cc] : 0.f;
        }
    }
    __syncthreads();

    int q2 = t >> 7, r = t & 127;
    int h = r >> 4, c2 = r & 15;
    int nq = b * 2 + q2, n = nq / LQ;
    const __bf16* vb = v + (size_t)n * LV * 256 + h * 32 + c2 * 2;
    float a0 = 0.f, a1 = 0.f;
    #pragma unroll
    for (int lp = 0; lp < 12; ++lp) {
        int idx = h * 12 + lp;
        #pragma unroll
        for (int cc = 0; cc < 4; ++cc) {
            float w = wgt[q2][idx][cc];
            int   e = offs[q2][idx][cc];
            ushort2 u = *(const ushort2*)&vb[e];
            a0 += w * __uint_as_float(((unsigned)u.x) << 16);
            a1 += w * __uint_as_float(((unsigned)u.y) << 16);
        }
    }
    float2 o = {a0, a1};
    *(float2*)&mid[(size_t)nq * 256 + h * 32 + c2 * 2] = o;
}

// ---------------------------------------------------------------------------
extern "C" void kernel_launch(void* const* d_in, const int* in_sizes, int n_in,
                              void* d_out, int out_size, void* d_ws, size_t ws_size,
                              hipStream_t stream)
{
    const float* query  = (const float*)d_in[0];
    const float* refp   = (const float*)d_in[1];
    const float* value  = (const float*)d_in[2];
    const float* W_off  = (const float*)d_in[3];
    const float* b_off  = (const float*)d_in[4];
    const float* W_attn = (const float*)d_in[5];
    const float* b_attn = (const float*)d_in[6];
    const float* W_val  = (const float*)d_in[7];
    const float* b_val  = (const float*)d_in[8];
    const float* W_out  = (const float*)d_in[9];
    const float* b_out  = (const float*)d_in[10];
    float* out = (float*)d_out;

    char* ws = (char*)d_ws;
    __bf16* v    = (__bf16*)ws;                                  // 68,812,800 B
    float*  offb = (float*)(ws + 68812800);                      //  3,686,400 B
    float*  awb  = (float*)(ws + 68812800 + 3686400);            //  1,843,200 B
    float*  mid  = (float*)(ws + 68812800 + 3686400 + 1843200);  //  4,915,200 B
    __bf16* Wtv  = (__bf16*)(ws + 68812800 + 3686400 + 1843200 + 4915200);
    __bf16* Wto  = Wtv + 65536;

    wtrans_kernel<<<dim3(8, 8, 2), 256, 0, stream>>>(W_val, W_out, Wtv, Wto);
    qproj_kernel<<<NB * LQ / 8, 256, 0, stream>>>(query, W_off, b_off, W_attn,
                                                  b_attn, offb, awb);
    // value projection: (134400 x 256) @ (256 x 256) + b_val -> bf16 v
    gemm_vproj<<<(NB * LV) / 128, 256, 0, stream>>>(value, Wtv, b_val, v);
    sample_kernel<<<NB * LQ / 2, 256, 0, stream>>>(v, offb, awb, refp, mid);
    // output projection: (4800 x 256) @ (256 x 256) + b_out -> fp32 out
    gemm_mfma<true, true><<<dim3(2, (NB * LQ + 127) / 128), 256, 0, stream>>>(
        mid, Wto, b_out, out, NB * LQ);
}